// Round 9
// baseline (116.726 us; speedup 1.0000x reference)
//
#include <hip/hip_runtime.h>
#include <hip/hip_bf16.h>

// y[n,g,h] = sum_k x[n,g,k] * H[g,k,h]
// x: [ntok, 4096] fp32, H: [64, 64, 64] fp32, y: [ntok, 4096] fp32.
// Memory-bound. R9 = R4 with ONE change: wave->group mapping. The 4 waves
// of a block now cover 4 ADJACENT groups at the SAME token tile, so each
// 1KB DRAM row (4 groups x 256B) is covered by co-resident lockstep waves
// in one shot, instead of 4 lone 256B chunks from 4 unrelated blocks
// (DRAM row activated ~4x per KB -> ~1x). Loads and NT stores both.

#define DIM 4096
#define NG   64   // groups per token
#define GSZ  64   // group size
#define TOK_PER_BLK 128   // 8 tiles x 16 tokens, shared by all 4 waves
#define TILES 8

typedef __bf16 bf16x8 __attribute__((ext_vector_type(8)));
typedef float  f32x4  __attribute__((ext_vector_type(4)));

__global__ __launch_bounds__(256, 4)
void hh_mfma_kernel(const float* __restrict__ x, const float* __restrict__ H,
                    float* __restrict__ y, int ntok) {
    const int wave = threadIdx.x >> 6;
    const int lane = threadIdx.x & 63;
    const int g    = (blockIdx.x & 15) * 4 + wave;   // 4 adjacent groups/block
    const int tb   = blockIdx.x >> 4;

    // ---- build H^T fragments (A operand) straight from global (L2-hot) ----
    const int hcol = lane & 15;
    const int hrow = (lane >> 4) * 8;
    const float* __restrict__ Hg = H + (size_t)g * (GSZ * GSZ);
    bf16x8 hfrag[2][4];
    #pragma unroll
    for (int kt = 0; kt < 2; ++kt)
        #pragma unroll
        for (int ht = 0; ht < 4; ++ht)
            #pragma unroll
            for (int i = 0; i < 8; ++i)
                hfrag[kt][ht][i] =
                    (__bf16)Hg[(kt * 32 + hrow + i) * GSZ + ht * 16 + hcol];

    // B operand = x^T tile: lane holds x[tok=lane&15][k=(lane>>4)*8+i]
    const int tokl  = lane & 15;
    const int acolk = (lane >> 4) * 8;
    const int hq    = (lane >> 4) * 4;   // C/D: col=token, row=4 consecutive h

    const int tok0 = tb * TOK_PER_BLK;               // waves SHARE tokens
    const float* __restrict__ xb =
        x + (size_t)(tok0 + tokl) * DIM + g * GSZ + acolk;
    float* __restrict__ yb =
        y + (size_t)(tok0 + tokl) * DIM + g * GSZ + hq;

    // raw[parity][4]: one tile = 4 f32x4
    f32x4 raw[2][4];
    #pragma unroll
    for (int kt = 0; kt < 2; ++kt) {
        raw[0][kt * 2 + 0] = *(const f32x4*)(xb + kt * 32);
        raw[0][kt * 2 + 1] = *(const f32x4*)(xb + kt * 32 + 4);
    }

    #pragma unroll
    for (int tt = 0; tt < TILES; ++tt) {
        // ---- issue next tile's loads first ----
        if (tt + 1 < TILES) {
            const float* __restrict__ xp = xb + (size_t)(tt + 1) * 16 * DIM;
            #pragma unroll
            for (int kt = 0; kt < 2; ++kt) {
                raw[(tt + 1) & 1][kt * 2 + 0] = *(const f32x4*)(xp + kt * 32);
                raw[(tt + 1) & 1][kt * 2 + 1] = *(const f32x4*)(xp + kt * 32 + 4);
            }
        }

        // ---- convert current tile to bf16 fragments ----
        bf16x8 xfrag[2];
        #pragma unroll
        for (int kt = 0; kt < 2; ++kt)
            #pragma unroll
            for (int i = 0; i < 4; ++i) {
                xfrag[kt][i]     = (__bf16)raw[tt & 1][kt * 2 + 0][i];
                xfrag[kt][i + 4] = (__bf16)raw[tt & 1][kt * 2 + 1][i];
            }

        // ---- 8 MFMAs: D[h][tok] = sum_k H^T[h][k] x^T[k][tok] ----
        f32x4 acc[4];
        #pragma unroll
        for (int ht = 0; ht < 4; ++ht) {
            acc[ht] = (f32x4){0.f, 0.f, 0.f, 0.f};
            acc[ht] = __builtin_amdgcn_mfma_f32_16x16x32_bf16(
                          hfrag[0][ht], xfrag[0], acc[ht], 0, 0, 0);
            acc[ht] = __builtin_amdgcn_mfma_f32_16x16x32_bf16(
                          hfrag[1][ht], xfrag[1], acc[ht], 0, 0, 0);
        }

        // ---- scattered NT stores (R4 pattern — best measured) ----
        float* __restrict__ yp = yb + (size_t)tt * 16 * DIM;
        #pragma unroll
        for (int ht = 0; ht < 4; ++ht)
            __builtin_nontemporal_store(acc[ht], (f32x4*)(yp + ht * 16));
    }
}

extern "C" void kernel_launch(void* const* d_in, const int* in_sizes, int n_in,
                              void* d_out, int out_size, void* d_ws, size_t ws_size,
                              hipStream_t stream) {
    const float* x = (const float*)d_in[0];
    const float* H = (const float*)d_in[1];
    float* y = (float*)d_out;

    const int ntok = in_sizes[0] / DIM;                  // 16384
    const int nblk = (ntok / TOK_PER_BLK) * (NG / 4);    // 128 * 16 = 2048

    hipLaunchKernelGGL(hh_mfma_kernel, dim3(nblk), dim3(256), 0, stream,
                       x, H, y, ntok);
}

// Round 10
// 98.968 us; speedup vs baseline: 1.1794x; 1.1794x over previous
//
#include <hip/hip_runtime.h>
#include <hip/hip_bf16.h>

// y[n,g,h] = sum_k x[n,g,k] * H[g,k,h]
// x: [ntok, 4096] fp32, H: [64, 64, 64] fp32, y: [ntok, 4096] fp32.
// Memory-bound. R10 = R4 with ONE change: k-PERMUTED load layout.
// MFMA's k-sum is permutation-invariant, so we reassign (lane,slot)->k as
//   slot i<4: k = q*4+i,  slot i>=4: k = 16+q*4+(i-4)   (q = lane>>4)
// making each load instruction cover a FULL contiguous 64B granule per
// token row (R4's layout touched each granule twice, half-filled: 2x the
// read request count). hfrag uses the same permutation -> results identical.

#define DIM 4096
#define NG   64   // groups per token
#define GSZ  64   // group size
#define TOK_PER_BLK 512
#define TILES 8   // 16-token tiles per wave

typedef __bf16 bf16x8 __attribute__((ext_vector_type(8)));
typedef float  f32x4  __attribute__((ext_vector_type(4)));

__global__ __launch_bounds__(256, 4)
void hh_mfma_kernel(const float* __restrict__ x, const float* __restrict__ H,
                    float* __restrict__ y, int ntok) {
    const int g    = blockIdx.x & (NG - 1);
    const int tb   = blockIdx.x >> 6;
    const int lane = threadIdx.x & 63;
    const int wave = threadIdx.x >> 6;
    const int q    = lane >> 4;          // lane quad-group
    const int tokl = lane & 15;          // token within tile (B-operand col)
    const int hcol = lane & 15;          // h within 16-tile (A-operand row)

    // ---- build H^T fragments (A operand) from global (L2-hot), with the
    //      SAME k-permutation the x-loads use ----
    const float* __restrict__ Hg = H + (size_t)g * (GSZ * GSZ);
    bf16x8 hfrag[2][4];
    #pragma unroll
    for (int kt = 0; kt < 2; ++kt)
        #pragma unroll
        for (int ht = 0; ht < 4; ++ht)
            #pragma unroll
            for (int i = 0; i < 8; ++i) {
                const int krow = kt * 32 + ((i < 4) ? (q * 4 + i)
                                                    : (16 + q * 4 + (i - 4)));
                hfrag[kt][ht][i] = (__bf16)Hg[krow * GSZ + ht * 16 + hcol];
            }

    const int hq = q * 4;                // C/D: col=token, row=4 consecutive h

    const int tok0 = tb * TOK_PER_BLK + wave * (16 * TILES);
    // lane's 16B chunks start at byte q*16 within the 256B group chunk:
    const float* __restrict__ xb =
        x + (size_t)(tok0 + tokl) * DIM + g * GSZ + q * 4;
    float* __restrict__ yb =
        y + (size_t)(tok0 + tokl) * DIM + g * GSZ + hq;

    // raw[parity][4]: one tile = 4 f32x4 per lane
    //   [kt*2+0] = k in [kt*32 + q*4 .. +4)       (granule [0,64) of half)
    //   [kt*2+1] = k in [kt*32 + 16 + q*4 .. +4)  (granule [64,128) of half)
    f32x4 raw[2][4];
    #pragma unroll
    for (int kt = 0; kt < 2; ++kt) {
        raw[0][kt * 2 + 0] = *(const f32x4*)(xb + kt * 32);
        raw[0][kt * 2 + 1] = *(const f32x4*)(xb + kt * 32 + 16);
    }

    #pragma unroll
    for (int tt = 0; tt < TILES; ++tt) {
        // ---- issue next tile's loads first ----
        if (tt + 1 < TILES) {
            const float* __restrict__ xp = xb + (size_t)(tt + 1) * 16 * DIM;
            #pragma unroll
            for (int kt = 0; kt < 2; ++kt) {
                raw[(tt + 1) & 1][kt * 2 + 0] = *(const f32x4*)(xp + kt * 32);
                raw[(tt + 1) & 1][kt * 2 + 1] = *(const f32x4*)(xp + kt * 32 + 16);
            }
        }

        // ---- convert current tile to bf16 fragments (permuted k order) ----
        bf16x8 xfrag[2];
        #pragma unroll
        for (int kt = 0; kt < 2; ++kt)
            #pragma unroll
            for (int i = 0; i < 4; ++i) {
                xfrag[kt][i]     = (__bf16)raw[tt & 1][kt * 2 + 0][i];
                xfrag[kt][i + 4] = (__bf16)raw[tt & 1][kt * 2 + 1][i];
            }

        // ---- 8 MFMAs: D[h][tok] = sum_k H^T[h][k] x^T[k][tok] ----
        f32x4 acc[4];
        #pragma unroll
        for (int ht = 0; ht < 4; ++ht) {
            acc[ht] = (f32x4){0.f, 0.f, 0.f, 0.f};
            acc[ht] = __builtin_amdgcn_mfma_f32_16x16x32_bf16(
                          hfrag[0][ht], xfrag[0], acc[ht], 0, 0, 0);
            acc[ht] = __builtin_amdgcn_mfma_f32_16x16x32_bf16(
                          hfrag[1][ht], xfrag[1], acc[ht], 0, 0, 0);
        }

        // ---- scattered NT stores (R4 pattern — best measured; each instr
        //      already writes full 64B granules per row) ----
        float* __restrict__ yp = yb + (size_t)tt * 16 * DIM;
        #pragma unroll
        for (int ht = 0; ht < 4; ++ht)
            __builtin_nontemporal_store(acc[ht], (f32x4*)(yp + ht * 16));
    }
}

extern "C" void kernel_launch(void* const* d_in, const int* in_sizes, int n_in,
                              void* d_out, int out_size, void* d_ws, size_t ws_size,
                              hipStream_t stream) {
    const float* x = (const float*)d_in[0];
    const float* H = (const float*)d_in[1];
    float* y = (float*)d_out;

    const int ntok = in_sizes[0] / DIM;             // 16384
    const int nblk = (ntok / TOK_PER_BLK) * NG;     // 32 * 64 = 2048

    hipLaunchKernelGGL(hh_mfma_kernel, dim3(nblk), dim3(256), 0, stream,
                       x, H, y, ntok);
}